// Round 2
// baseline (423.912 us; speedup 1.0000x reference)
//
#include <hip/hip_runtime.h>

// Problem constants (match reference): B=16, T=4096, E=768.
constexpr int Bc = 16;
constexpr int Tc = 4096;
constexpr int Ec = 768;
constexpr int PSTRIDE = Ec + 2;     // per-partial: [m, l, o[768]]
constexpr int CTR_FLOATS = 32;      // first 128 B of ws reserved for counters

// Fast accurate-enough tanh: tanh(x) = (e^2x - 1)/(e^2x + 1), v_exp + v_rcp.
__device__ __forceinline__ float fast_tanh(float x) {
    x = fminf(15.0f, fmaxf(-15.0f, x));           // avoid inf/inf
    float e = __expf(2.0f * x);                   // v_exp_f32 path
    return (e - 1.0f) * __builtin_amdgcn_rcpf(e + 1.0f);
}

__device__ __forceinline__ float dot_tanh4(float4 c, float4 w) {
    float s;
    s = fast_tanh(c.x) * w.x;
    s = fmaf(fast_tanh(c.y), w.y, s);
    s = fmaf(fast_tanh(c.z), w.z, s);
    s = fmaf(fast_tanh(c.w), w.w, s);
    return s;
}

__device__ __forceinline__ float4 upd4(float4 o, float alpha, float p, float4 c) {
    return make_float4(fmaf(o.x, alpha, p * c.x),
                       fmaf(o.y, alpha, p * c.y),
                       fmaf(o.z, alpha, p * c.z),
                       fmaf(o.w, alpha, p * c.w));
}

// Fused kernel: per (b, chunk) block, flash-style online softmax-weighted sum
// over the chunk's rows (one wave per row-group; lane owns e = j*256+4*lane..+3).
// Softmax shift-invariance => tanh(query)·v_w[:E] term dropped (exact).
// Masked rows skipped entirely (exact: exp(-1e10 - m) == 0 in fp32).
// Last block per batch (atomic counter) performs the cross-chunk combine —
// no second kernel launch.
template<int C>
__global__ __launch_bounds__(256) void attn_fused(
    const float* __restrict__ ctx, const int* __restrict__ mask,
    const float* __restrict__ v_w, int* __restrict__ counters,
    float* __restrict__ parts, float* __restrict__ out)
{
    constexpr int ROWS_PER_BLOCK = Tc / C;
    constexpr int R = ROWS_PER_BLOCK / 4;     // rows per wave
    const int b    = blockIdx.x / C;
    const int c    = blockIdx.x % C;
    const int wave = threadIdx.x >> 6;
    const int lane = threadIdx.x & 63;

    // Preload second half of v_w for this lane's e-slice.
    float4 vw[3];
#pragma unroll
    for (int j = 0; j < 3; ++j)
        vw[j] = *reinterpret_cast<const float4*>(v_w + Ec + j * 256 + 4 * lane);

    float m = -1e30f, l = 0.0f;
    float4 o0 = make_float4(0.f, 0.f, 0.f, 0.f), o1 = o0, o2 = o0;

    const int  row0  = c * ROWS_PER_BLOCK + wave * R;
    const long cbase = (long)b * Tc * Ec;

    for (int g = 0; g < R; g += 64) {
        // Prefetch up to 64 row masks across lanes; broadcast via shfl.
        int tl = row0 + g + lane;
        tl = tl < (Tc - 1) ? tl : (Tc - 1);
        const int mv = mask[b * Tc + tl];
        const int nr = (R - g < 64) ? (R - g) : 64;
        for (int r = 0; r < nr; ++r) {
            if (__shfl(mv, r, 64) == 0) continue;   // wave-uniform skip
            const int t = row0 + g + r;
            const float* rowp = ctx + cbase + (long)t * Ec + 4 * lane;
            float4 cv0 = *reinterpret_cast<const float4*>(rowp);
            float4 cv1 = *reinterpret_cast<const float4*>(rowp + 256);
            float4 cv2 = *reinterpret_cast<const float4*>(rowp + 512);

            float s = dot_tanh4(cv0, vw[0]);
            s += dot_tanh4(cv1, vw[1]);
            s += dot_tanh4(cv2, vw[2]);
#pragma unroll
            for (int off = 32; off > 0; off >>= 1)
                s += __shfl_xor(s, off, 64);        // all lanes get the score

            float mn    = fmaxf(m, s);
            float alpha = __expf(m - mn);
            float p     = __expf(s - mn);
            l  = fmaf(l, alpha, p);
            o0 = upd4(o0, alpha, p, cv0);
            o1 = upd4(o1, alpha, p, cv1);
            o2 = upd4(o2, alpha, p, cv2);
            m  = mn;
        }
    }

    // Combine the block's 4 wave partials in LDS, write one block partial.
    __shared__ float sm[4], sl[4];
    __shared__ float so[4][Ec];
    if (lane == 0) { sm[wave] = m; sl[wave] = l; }
    __syncthreads();
    float M = fmaxf(fmaxf(sm[0], sm[1]), fmaxf(sm[2], sm[3]));
    float wscale = __expf(m - M);   // m is wave-uniform
    {
        float4 t0 = make_float4(o0.x * wscale, o0.y * wscale, o0.z * wscale, o0.w * wscale);
        float4 t1 = make_float4(o1.x * wscale, o1.y * wscale, o1.z * wscale, o1.w * wscale);
        float4 t2 = make_float4(o2.x * wscale, o2.y * wscale, o2.z * wscale, o2.w * wscale);
        *reinterpret_cast<float4*>(&so[wave][0 * 256 + 4 * lane]) = t0;
        *reinterpret_cast<float4*>(&so[wave][1 * 256 + 4 * lane]) = t1;
        *reinterpret_cast<float4*>(&so[wave][2 * 256 + 4 * lane]) = t2;
    }
    __syncthreads();

    float* part = parts + ((long)b * C + c) * PSTRIDE;
    if (threadIdx.x == 0) {
        part[0] = M;
        part[1] = sl[0] * __expf(sm[0] - M) + sl[1] * __expf(sm[1] - M)
                + sl[2] * __expf(sm[2] - M) + sl[3] * __expf(sm[3] - M);
    }
#pragma unroll
    for (int j = 0; j < 3; ++j) {
        int e = threadIdx.x + j * 256;
        part[2 + e] = so[0][e] + so[1][e] + so[2][e] + so[3][e];
    }

    // ---- last-block-per-batch combine (rocPRIM pattern) ----
    __threadfence();                               // release partial writes
    __shared__ int lastFlag;
    if (threadIdx.x == 0) {
        int old = atomicAdd(&counters[b], 1);      // device-scope
        lastFlag = (old == C - 1);
    }
    __syncthreads();
    if (!lastFlag) return;
    __threadfence();                               // acquire others' partials

    const float* pb = parts + (long)b * C * PSTRIDE;
    __shared__ float rm[C], rw[C], rwl[C];
    if (threadIdx.x < C) rm[threadIdx.x] = pb[threadIdx.x * PSTRIDE];
    __syncthreads();
    float GM = -1e30f;
    for (int k = 0; k < C; ++k) GM = fmaxf(GM, rm[k]);
    if (threadIdx.x < C) {
        float wv = __expf(rm[threadIdx.x] - GM);
        rw[threadIdx.x]  = wv;
        rwl[threadIdx.x] = wv * pb[threadIdx.x * PSTRIDE + 1];
    }
    __syncthreads();

    float lsum = 0.f;
    for (int k = 0; k < C; ++k) lsum += rwl[k];
    const float rls = __builtin_amdgcn_rcpf(lsum);

#pragma unroll
    for (int j = 0; j < 3; ++j) {
        const int e = threadIdx.x + j * 256;
        float acc = 0.f;
        for (int k = 0; k < C; ++k)
            acc = fmaf(rw[k], pb[k * PSTRIDE + 2 + e], acc);
        out[b * Ec + e] = acc * rls;
    }
}

template<int C>
static void run_pipeline(const float* ctx, const int* mask, const float* vw,
                         float* ws, float* out, hipStream_t stream)
{
    int*   counters = (int*)ws;
    float* parts    = ws + CTR_FLOATS;
    hipMemsetAsync(ws, 0, CTR_FLOATS * sizeof(float), stream);  // zero counters (capturable)
    attn_fused<C><<<dim3(Bc * C), 256, 0, stream>>>(ctx, mask, vw, counters, parts, out);
}

extern "C" void kernel_launch(void* const* d_in, const int* in_sizes, int n_in,
                              void* d_out, int out_size, void* d_ws, size_t ws_size,
                              hipStream_t stream)
{
    (void)in_sizes; (void)n_in; (void)out_size;
    // setup_inputs order: query[0] (unused — softmax shift-invariant),
    // context[1], mask[2], v_w[3].
    const float* ctx  = (const float*)d_in[1];
    const int*   mask = (const int*)d_in[2];
    const float* vw   = (const float*)d_in[3];
    float* out = (float*)d_out;
    float* ws  = (float*)d_ws;

    const size_t base = CTR_FLOATS * sizeof(float);
    const size_t need64 = base + (size_t)Bc * 64 * PSTRIDE * sizeof(float);
    const size_t need16 = base + (size_t)Bc * 16 * PSTRIDE * sizeof(float);
    const size_t need4  = base + (size_t)Bc * 4  * PSTRIDE * sizeof(float);

    if (ws_size >= need64)      run_pipeline<64>(ctx, mask, vw, ws, out, stream);
    else if (ws_size >= need16) run_pipeline<16>(ctx, mask, vw, ws, out, stream);
    else if (ws_size >= need4)  run_pipeline<4>(ctx, mask, vw, ws, out, stream);
    else                        run_pipeline<1>(ctx, mask, vw, ws, out, stream);
}

// Round 3
// 267.596 us; speedup vs baseline: 1.5841x; 1.5841x over previous
//
#include <hip/hip_runtime.h>

// Problem constants (match reference): B=16, T=4096, E=768.
constexpr int Bc = 16;
constexpr int Tc = 4096;
constexpr int Ec = 768;
constexpr int PSTRIDE = Ec + 4;   // per-partial: [l, pad, pad, pad, o[768]] (16B-aligned o)

// tanh(x) = 1 - 2/(e^2x + 1): clamp + mul + exp + add + rcp + fma = 6 VALU ops.
__device__ __forceinline__ float fast_tanh(float x) {
    x = fminf(12.0f, fmaxf(-12.0f, x));
    float e = __expf(2.0f * x);
    return fmaf(-2.0f, __builtin_amdgcn_rcpf(e + 1.0f), 1.0f);
}

__device__ __forceinline__ float dot_tanh4(float4 c, float4 w) {
    float s;
    s = fast_tanh(c.x) * w.x;
    s = fmaf(fast_tanh(c.y), w.y, s);
    s = fmaf(fast_tanh(c.z), w.z, s);
    s = fmaf(fast_tanh(c.w), w.w, s);
    return s;
}

__device__ __forceinline__ float4 upd4(float4 o, float p, float4 c) {
    return make_float4(fmaf(p, c.x, o.x), fmaf(p, c.y, o.y),
                       fmaf(p, c.z, o.z), fmaf(p, c.w, o.w));
}

// Kernel 1: per (b, chunk) block, UNSHIFTED softmax accumulation.
// |score| <= sum|v_w[E:]| ~ 15.7 so e^s never overflows/underflows fp32;
// softmax shift-invariance also drops the tanh(query).v_w[:E] term (exact).
// Masked rows skipped exactly (exp(-1e10-m)==0 in fp32): ballot-compact the
// unmasked rows per wave (wave-uniform, no divergence) and software-pipeline
// with a 1-row-ahead prefetch. Partials combine by plain addition later.
template<int C>
__global__ __launch_bounds__(256, 4) void attn_partial(
    const float* __restrict__ ctx, const int* __restrict__ mask,
    const float* __restrict__ v_w, float* __restrict__ parts)
{
    constexpr int RPB = Tc / C;        // rows per block
    constexpr int R   = RPB / 4;       // rows per wave
    const int b    = blockIdx.x / C;
    const int c    = blockIdx.x % C;
    const int wave = threadIdx.x >> 6;
    const int lane = threadIdx.x & 63;

    const float4 vw0 = *reinterpret_cast<const float4*>(v_w + Ec + 0 * 256 + 4 * lane);
    const float4 vw1 = *reinterpret_cast<const float4*>(v_w + Ec + 1 * 256 + 4 * lane);
    const float4 vw2 = *reinterpret_cast<const float4*>(v_w + Ec + 2 * 256 + 4 * lane);

    float  l  = 0.0f;
    float4 o0 = make_float4(0.f, 0.f, 0.f, 0.f), o1 = o0, o2 = o0;

    const int    row0 = c * RPB + wave * R;
    const float* cb   = ctx + (long)b * Tc * Ec;

    for (int g = 0; g < R; g += 64) {
        const int n = (R - g < 64) ? (R - g) : 64;
        // row0+g+lane < Tc always (last wave's window ends at Tc-1), so safe.
        const int mv = mask[b * Tc + row0 + g + lane];
        unsigned long long mb = __ballot(lane < n && mv != 0);   // wave-uniform
        if (!mb) continue;

        int r = __ffsll((long long)mb) - 1; mb &= mb - 1;
        const float* p = cb + (long)(row0 + g + r) * Ec + 4 * lane;
        float4 a0 = *reinterpret_cast<const float4*>(p);
        float4 a1 = *reinterpret_cast<const float4*>(p + 256);
        float4 a2 = *reinterpret_cast<const float4*>(p + 512);

        while (true) {
            const bool more = (mb != 0);
            float4 n0, n1, n2;
            if (more) {                 // prefetch next unmasked row
                int r2 = __ffsll((long long)mb) - 1; mb &= mb - 1;
                const float* q = cb + (long)(row0 + g + r2) * Ec + 4 * lane;
                n0 = *reinterpret_cast<const float4*>(q);
                n1 = *reinterpret_cast<const float4*>(q + 256);
                n2 = *reinterpret_cast<const float4*>(q + 512);
            }
            float s = dot_tanh4(a0, vw0) + dot_tanh4(a1, vw1) + dot_tanh4(a2, vw2);
#pragma unroll
            for (int off = 32; off > 0; off >>= 1)
                s += __shfl_xor(s, off, 64);
            const float pw = __expf(s);
            l += pw;
            o0 = upd4(o0, pw, a0);
            o1 = upd4(o1, pw, a1);
            o2 = upd4(o2, pw, a2);
            if (!more) break;
            a0 = n0; a1 = n1; a2 = n2;
        }
    }

    // Combine the block's 4 wave partials in LDS (plain sums), write one partial.
    __shared__ float sl[4];
    __shared__ float so[4][Ec];
    if (lane == 0) sl[wave] = l;
    *reinterpret_cast<float4*>(&so[wave][0 * 256 + 4 * lane]) = o0;
    *reinterpret_cast<float4*>(&so[wave][1 * 256 + 4 * lane]) = o1;
    *reinterpret_cast<float4*>(&so[wave][2 * 256 + 4 * lane]) = o2;
    __syncthreads();

    float* part = parts + ((long)b * C + c) * PSTRIDE;
    if (threadIdx.x == 0) part[0] = sl[0] + sl[1] + sl[2] + sl[3];
    if (threadIdx.x < 192) {
        const int e = 4 * threadIdx.x;
        float4 s0 = *reinterpret_cast<float4*>(&so[0][e]);
        float4 s1 = *reinterpret_cast<float4*>(&so[1][e]);
        float4 s2 = *reinterpret_cast<float4*>(&so[2][e]);
        float4 s3 = *reinterpret_cast<float4*>(&so[3][e]);
        float4 rs = make_float4(s0.x + s1.x + s2.x + s3.x,
                                s0.y + s1.y + s2.y + s3.y,
                                s0.z + s1.z + s2.z + s3.z,
                                s0.w + s1.w + s2.w + s3.w);
        *reinterpret_cast<float4*>(part + 4 + e) = rs;
    }
}

// Kernel 2: plain-sum combine of C partials per batch row + one divide.
// grid = (B, 3); each block handles 256 output features.
template<int C>
__global__ __launch_bounds__(256) void attn_reduce(
    const float* __restrict__ parts, float* __restrict__ out)
{
    const int b   = blockIdx.x;
    const int tid = threadIdx.x;
    const float* pb = parts + (long)b * C * PSTRIDE;

    float lsum = 0.0f;
    for (int k = 0; k < C; ++k) lsum += pb[k * PSTRIDE];

    const int e = blockIdx.y * 256 + tid;
    float acc = 0.0f;
    for (int k = 0; k < C; ++k) acc += pb[k * PSTRIDE + 4 + e];

    out[b * Ec + e] = acc / lsum;
}

template<int C>
static void run_pipeline(const float* ctx, const int* mask, const float* vw,
                         float* ws, float* out, hipStream_t stream)
{
    attn_partial<C><<<dim3(Bc * C), 256, 0, stream>>>(ctx, mask, vw, ws);
    attn_reduce<C><<<dim3(Bc, 3), 256, 0, stream>>>(ws, out);
}

extern "C" void kernel_launch(void* const* d_in, const int* in_sizes, int n_in,
                              void* d_out, int out_size, void* d_ws, size_t ws_size,
                              hipStream_t stream)
{
    (void)in_sizes; (void)n_in; (void)out_size;
    // setup_inputs order: query[0] (unused — softmax shift-invariant),
    // context[1], mask[2], v_w[3].
    const float* ctx  = (const float*)d_in[1];
    const int*   mask = (const int*)d_in[2];
    const float* vw   = (const float*)d_in[3];
    float* out = (float*)d_out;
    float* ws  = (float*)d_ws;

    const size_t need64 = (size_t)Bc * 64 * PSTRIDE * sizeof(float);
    const size_t need16 = (size_t)Bc * 16 * PSTRIDE * sizeof(float);
    const size_t need4  = (size_t)Bc * 4  * PSTRIDE * sizeof(float);

    if (ws_size >= need64)      run_pipeline<64>(ctx, mask, vw, ws, out, stream);
    else if (ws_size >= need16) run_pipeline<16>(ctx, mask, vw, ws, out, stream);
    else if (ws_size >= need4)  run_pipeline<4>(ctx, mask, vw, ws, out, stream);
    else                        run_pipeline<1>(ctx, mask, vw, ws, out, stream);
}

// Round 4
// 264.248 us; speedup vs baseline: 1.6042x; 1.0127x over previous
//
#include <hip/hip_runtime.h>

// Problem constants (match reference): B=16, T=4096, E=768.
constexpr int Bc = 16;
constexpr int Tc = 4096;
constexpr int Ec = 768;
constexpr int PSTRIDE = Ec + 4;   // per-partial: [l, pad, pad, pad, o[768]] (16B-aligned o)

// tanh(x) = 1 - 2/(e^2x + 1)
__device__ __forceinline__ float fast_tanh(float x) {
    x = fminf(12.0f, fmaxf(-12.0f, x));
    float e = __expf(2.0f * x);
    return fmaf(-2.0f, __builtin_amdgcn_rcpf(e + 1.0f), 1.0f);
}

__device__ __forceinline__ float dot_tanh4(float4 c, float4 w) {
    float s = fast_tanh(c.x) * w.x;
    s = fmaf(fast_tanh(c.y), w.y, s);
    s = fmaf(fast_tanh(c.z), w.z, s);
    s = fmaf(fast_tanh(c.w), w.w, s);
    return s;
}

__device__ __forceinline__ float4 ld4(const float* p) {
    return *reinterpret_cast<const float4*>(p);
}

// Kernel 1: per (b, chunk) block, UNSHIFTED softmax accumulation.
// |score| <= sum|v_w[E:]| ~ 15.7 so e^s is always in fp32 range (no max-shift
// needed); softmax shift-invariance drops the tanh(query).v_w[:E] term (exact).
// Masked rows skipped exactly (exp(-1e10-m)==0 in fp32): ballot-compact the
// unmasked rows per wave (wave-uniform), then process rows in PAIRS with a
// one-pair-ahead software pipeline: 12 float4 loads in flight per wave, two
// interleaved shfl-reduce chains. Partials combine by plain addition in k2.
template<int C>
__global__ __launch_bounds__(256, 4) void attn_partial(
    const float* __restrict__ ctx, const int* __restrict__ mask,
    const float* __restrict__ v_w, float* __restrict__ parts)
{
    constexpr int RPB = Tc / C;        // rows per block
    constexpr int R   = RPB / 4;       // rows per wave
    const int b    = blockIdx.x / C;
    const int c    = blockIdx.x % C;
    const int wave = threadIdx.x >> 6;
    const int lane = threadIdx.x & 63;

    const float4 vw0 = ld4(v_w + Ec + 0 * 256 + 4 * lane);
    const float4 vw1 = ld4(v_w + Ec + 1 * 256 + 4 * lane);
    const float4 vw2 = ld4(v_w + Ec + 2 * 256 + 4 * lane);

    float  l  = 0.0f;
    float4 o0 = make_float4(0.f, 0.f, 0.f, 0.f), o1 = o0, o2 = o0;

    const int    row0 = c * RPB + wave * R;
    const float* cb   = ctx + (long)b * Tc * Ec;

    for (int g = 0; g < R; g += 64) {
        const int n  = (R - g < 64) ? (R - g) : 64;
        const int li = (lane < n) ? lane : 0;                  // clamp (no OOB)
        const int mv = mask[b * Tc + row0 + g + li];
        unsigned long long mb = __ballot(lane < n && mv != 0); // wave-uniform
        const int cnt = __popcll(mb);
        if (!cnt) continue;

        auto pop = [&]() -> const float* {
            int r = (int)__ffsll((long long)mb) - 1; mb &= mb - 1;
            return cb + (long)(row0 + g + r) * Ec + 4 * lane;
        };

        // process one pair of rows held in (a0..a5)
        float4 a0, a1, a2, a3, a4, a5;
        auto compute_pair = [&]() {
            float s0 = dot_tanh4(a0, vw0) + dot_tanh4(a1, vw1) + dot_tanh4(a2, vw2);
            float s1 = dot_tanh4(a3, vw0) + dot_tanh4(a4, vw1) + dot_tanh4(a5, vw2);
#pragma unroll
            for (int off = 32; off > 0; off >>= 1) {           // two chains interleave
                s0 += __shfl_xor(s0, off, 64);
                s1 += __shfl_xor(s1, off, 64);
            }
            const float p0 = __expf(s0), p1 = __expf(s1);
            l += p0 + p1;
            o0.x = fmaf(p0, a0.x, fmaf(p1, a3.x, o0.x));
            o0.y = fmaf(p0, a0.y, fmaf(p1, a3.y, o0.y));
            o0.z = fmaf(p0, a0.z, fmaf(p1, a3.z, o0.z));
            o0.w = fmaf(p0, a0.w, fmaf(p1, a3.w, o0.w));
            o1.x = fmaf(p0, a1.x, fmaf(p1, a4.x, o1.x));
            o1.y = fmaf(p0, a1.y, fmaf(p1, a4.y, o1.y));
            o1.z = fmaf(p0, a1.z, fmaf(p1, a4.z, o1.z));
            o1.w = fmaf(p0, a1.w, fmaf(p1, a4.w, o1.w));
            o2.x = fmaf(p0, a2.x, fmaf(p1, a5.x, o2.x));
            o2.y = fmaf(p0, a2.y, fmaf(p1, a5.y, o2.y));
            o2.z = fmaf(p0, a2.z, fmaf(p1, a5.z, o2.z));
            o2.w = fmaf(p0, a2.w, fmaf(p1, a5.w, o2.w));
        };

        const int pairs = cnt >> 1;
        if (pairs) {
            { const float* p = pop(); a0 = ld4(p); a1 = ld4(p + 256); a2 = ld4(p + 512);
              const float* q = pop(); a3 = ld4(q); a4 = ld4(q + 256); a5 = ld4(q + 512); }
            for (int pi = 1; pi < pairs; ++pi) {
                // issue next pair's 6 loads before computing current pair
                const float* p = pop();
                float4 n0 = ld4(p), n1 = ld4(p + 256), n2 = ld4(p + 512);
                const float* q = pop();
                float4 n3 = ld4(q), n4 = ld4(q + 256), n5 = ld4(q + 512);
                compute_pair();
                a0 = n0; a1 = n1; a2 = n2; a3 = n3; a4 = n4; a5 = n5;
            }
            compute_pair();
        }
        if (cnt & 1) {                                          // odd tail row
            const float* p = pop();
            a0 = ld4(p); a1 = ld4(p + 256); a2 = ld4(p + 512);
            float s = dot_tanh4(a0, vw0) + dot_tanh4(a1, vw1) + dot_tanh4(a2, vw2);
#pragma unroll
            for (int off = 32; off > 0; off >>= 1)
                s += __shfl_xor(s, off, 64);
            const float pw = __expf(s);
            l += pw;
            o0.x = fmaf(pw, a0.x, o0.x); o0.y = fmaf(pw, a0.y, o0.y);
            o0.z = fmaf(pw, a0.z, o0.z); o0.w = fmaf(pw, a0.w, o0.w);
            o1.x = fmaf(pw, a1.x, o1.x); o1.y = fmaf(pw, a1.y, o1.y);
            o1.z = fmaf(pw, a1.z, o1.z); o1.w = fmaf(pw, a1.w, o1.w);
            o2.x = fmaf(pw, a2.x, o2.x); o2.y = fmaf(pw, a2.y, o2.y);
            o2.z = fmaf(pw, a2.z, o2.z); o2.w = fmaf(pw, a2.w, o2.w);
        }
    }

    // Combine the block's 4 wave partials in LDS (plain sums), write one partial.
    __shared__ float sl[4];
    __shared__ float so[4][Ec];
    if (lane == 0) sl[wave] = l;
    *reinterpret_cast<float4*>(&so[wave][0 * 256 + 4 * lane]) = o0;
    *reinterpret_cast<float4*>(&so[wave][1 * 256 + 4 * lane]) = o1;
    *reinterpret_cast<float4*>(&so[wave][2 * 256 + 4 * lane]) = o2;
    __syncthreads();

    float* part = parts + ((long)b * C + c) * PSTRIDE;
    if (threadIdx.x == 0) part[0] = sl[0] + sl[1] + sl[2] + sl[3];
    if (threadIdx.x < 192) {
        const int e = 4 * threadIdx.x;
        float4 s0 = *reinterpret_cast<float4*>(&so[0][e]);
        float4 s1 = *reinterpret_cast<float4*>(&so[1][e]);
        float4 s2 = *reinterpret_cast<float4*>(&so[2][e]);
        float4 s3 = *reinterpret_cast<float4*>(&so[3][e]);
        float4 rs = make_float4(s0.x + s1.x + s2.x + s3.x,
                                s0.y + s1.y + s2.y + s3.y,
                                s0.z + s1.z + s2.z + s3.z,
                                s0.w + s1.w + s2.w + s3.w);
        *reinterpret_cast<float4*>(part + 4 + e) = rs;
    }
}

// Kernel 2: plain-sum combine of C partials per batch row + one divide.
// grid = (B, 3); each block handles 256 output features.
template<int C>
__global__ __launch_bounds__(256) void attn_reduce(
    const float* __restrict__ parts, float* __restrict__ out)
{
    const int b   = blockIdx.x;
    const int tid = threadIdx.x;
    const float* pb = parts + (long)b * C * PSTRIDE;

    float lsum = 0.0f;
    for (int k = 0; k < C; ++k) lsum += pb[k * PSTRIDE];

    const int e = blockIdx.y * 256 + tid;
    float acc = 0.0f;
    for (int k = 0; k < C; ++k) acc += pb[k * PSTRIDE + 4 + e];

    out[b * Ec + e] = acc / lsum;
}

template<int C>
static void run_pipeline(const float* ctx, const int* mask, const float* vw,
                         float* ws, float* out, hipStream_t stream)
{
    attn_partial<C><<<dim3(Bc * C), 256, 0, stream>>>(ctx, mask, vw, ws);
    attn_reduce<C><<<dim3(Bc, 3), 256, 0, stream>>>(ws, out);
}

extern "C" void kernel_launch(void* const* d_in, const int* in_sizes, int n_in,
                              void* d_out, int out_size, void* d_ws, size_t ws_size,
                              hipStream_t stream)
{
    (void)in_sizes; (void)n_in; (void)out_size;
    // setup_inputs order: query[0] (unused — softmax shift-invariant),
    // context[1], mask[2], v_w[3].
    const float* ctx  = (const float*)d_in[1];
    const int*   mask = (const int*)d_in[2];
    const float* vw   = (const float*)d_in[3];
    float* out = (float*)d_out;
    float* ws  = (float*)d_ws;

    const size_t need64 = (size_t)Bc * 64 * PSTRIDE * sizeof(float);
    const size_t need16 = (size_t)Bc * 16 * PSTRIDE * sizeof(float);
    const size_t need4  = (size_t)Bc * 4  * PSTRIDE * sizeof(float);

    if (ws_size >= need64)      run_pipeline<64>(ctx, mask, vw, ws, out, stream);
    else if (ws_size >= need16) run_pipeline<16>(ctx, mask, vw, ws, out, stream);
    else if (ws_size >= need4)  run_pipeline<4>(ctx, mask, vw, ws, out, stream);
    else                        run_pipeline<1>(ctx, mask, vw, ws, out, stream);
}

// Round 5
// 249.855 us; speedup vs baseline: 1.6966x; 1.0576x over previous
//
#include <hip/hip_runtime.h>

// Problem constants (match reference): B=16, T=4096, E=768.
constexpr int Bc = 16;
constexpr int Tc = 4096;
constexpr int Ec = 768;
constexpr int PSTRIDE = Ec + 4;   // per-partial: [l, pad, pad, pad, o[768]] (16B-aligned o)

// tanh(x) = 1 - 2/(e^2x + 1)
__device__ __forceinline__ float fast_tanh(float x) {
    x = fminf(12.0f, fmaxf(-12.0f, x));
    float e = __expf(2.0f * x);
    return fmaf(-2.0f, __builtin_amdgcn_rcpf(e + 1.0f), 1.0f);
}

__device__ __forceinline__ float dot_tanh4(float4 c, float4 w) {
    float s = fast_tanh(c.x) * w.x;
    s = fmaf(fast_tanh(c.y), w.y, s);
    s = fmaf(fast_tanh(c.z), w.z, s);
    s = fmaf(fast_tanh(c.w), w.w, s);
    return s;
}

__device__ __forceinline__ float4 ld4(const float* p) {
    return *reinterpret_cast<const float4*>(p);
}

// Non-temporal 16B load: no L3 allocate -> no dirty 0xAA-line eviction stall,
// and context (zero-reuse) doesn't pollute L3. Emits global_load_dwordx4 ... nt.
using vf4 = __attribute__((ext_vector_type(4))) float;
__device__ __forceinline__ float4 ldnt4(const float* p) {
    vf4 v = __builtin_nontemporal_load(reinterpret_cast<const vf4*>(p));
    return make_float4(v.x, v.y, v.z, v.w);
}

// Kernel 1: per (b, chunk) block, UNSHIFTED softmax accumulation.
// |score| <= sum|v_w[E:]| ~ 15.7 so e^s is always in fp32 range (no max-shift
// needed); softmax shift-invariance drops the tanh(query).v_w[:E] term (exact).
// Masked rows skipped exactly (exp(-1e10-m)==0 in fp32): ballot-compact the
// unmasked rows per wave (wave-uniform), process rows in PAIRS with a
// one-pair-ahead software pipeline, context via non-temporal loads.
template<int C>
__global__ __launch_bounds__(256, 4) void attn_partial(
    const float* __restrict__ ctx, const int* __restrict__ mask,
    const float* __restrict__ v_w, float* __restrict__ parts)
{
    constexpr int RPB = Tc / C;        // rows per block
    constexpr int R   = RPB / 4;       // rows per wave
    const int b    = blockIdx.x / C;
    const int c    = blockIdx.x % C;
    const int wave = threadIdx.x >> 6;
    const int lane = threadIdx.x & 63;

    const float4 vw0 = ld4(v_w + Ec + 0 * 256 + 4 * lane);
    const float4 vw1 = ld4(v_w + Ec + 1 * 256 + 4 * lane);
    const float4 vw2 = ld4(v_w + Ec + 2 * 256 + 4 * lane);

    float  l  = 0.0f;
    float4 o0 = make_float4(0.f, 0.f, 0.f, 0.f), o1 = o0, o2 = o0;

    const int    row0 = c * RPB + wave * R;
    const float* cb   = ctx + (long)b * Tc * Ec;

    for (int g = 0; g < R; g += 64) {
        const int n  = (R - g < 64) ? (R - g) : 64;
        const int li = (lane < n) ? lane : 0;                  // clamp (no OOB)
        const int mv = mask[b * Tc + row0 + g + li];
        unsigned long long mb = __ballot(lane < n && mv != 0); // wave-uniform
        const int cnt = __popcll(mb);
        if (!cnt) continue;

        auto pop = [&]() -> const float* {
            int r = (int)__ffsll((long long)mb) - 1; mb &= mb - 1;
            return cb + (long)(row0 + g + r) * Ec + 4 * lane;
        };

        float4 a0, a1, a2, a3, a4, a5;
        auto compute_pair = [&]() {
            float s0 = dot_tanh4(a0, vw0) + dot_tanh4(a1, vw1) + dot_tanh4(a2, vw2);
            float s1 = dot_tanh4(a3, vw0) + dot_tanh4(a4, vw1) + dot_tanh4(a5, vw2);
#pragma unroll
            for (int off = 32; off > 0; off >>= 1) {           // two chains interleave
                s0 += __shfl_xor(s0, off, 64);
                s1 += __shfl_xor(s1, off, 64);
            }
            const float p0 = __expf(s0), p1 = __expf(s1);
            l += p0 + p1;
            o0.x = fmaf(p0, a0.x, fmaf(p1, a3.x, o0.x));
            o0.y = fmaf(p0, a0.y, fmaf(p1, a3.y, o0.y));
            o0.z = fmaf(p0, a0.z, fmaf(p1, a3.z, o0.z));
            o0.w = fmaf(p0, a0.w, fmaf(p1, a3.w, o0.w));
            o1.x = fmaf(p0, a1.x, fmaf(p1, a4.x, o1.x));
            o1.y = fmaf(p0, a1.y, fmaf(p1, a4.y, o1.y));
            o1.z = fmaf(p0, a1.z, fmaf(p1, a4.z, o1.z));
            o1.w = fmaf(p0, a1.w, fmaf(p1, a4.w, o1.w));
            o2.x = fmaf(p0, a2.x, fmaf(p1, a5.x, o2.x));
            o2.y = fmaf(p0, a2.y, fmaf(p1, a5.y, o2.y));
            o2.z = fmaf(p0, a2.z, fmaf(p1, a5.z, o2.z));
            o2.w = fmaf(p0, a2.w, fmaf(p1, a5.w, o2.w));
        };

        const int pairs = cnt >> 1;
        if (pairs) {
            { const float* p = pop(); a0 = ldnt4(p); a1 = ldnt4(p + 256); a2 = ldnt4(p + 512);
              const float* q = pop(); a3 = ldnt4(q); a4 = ldnt4(q + 256); a5 = ldnt4(q + 512); }
            for (int pi = 1; pi < pairs; ++pi) {
                const float* p = pop();
                float4 n0 = ldnt4(p), n1 = ldnt4(p + 256), n2 = ldnt4(p + 512);
                const float* q = pop();
                float4 n3 = ldnt4(q), n4 = ldnt4(q + 256), n5 = ldnt4(q + 512);
                compute_pair();
                a0 = n0; a1 = n1; a2 = n2; a3 = n3; a4 = n4; a5 = n5;
            }
            compute_pair();
        }
        if (cnt & 1) {                                          // odd tail row
            const float* p = pop();
            a0 = ldnt4(p); a1 = ldnt4(p + 256); a2 = ldnt4(p + 512);
            float s = dot_tanh4(a0, vw0) + dot_tanh4(a1, vw1) + dot_tanh4(a2, vw2);
#pragma unroll
            for (int off = 32; off > 0; off >>= 1)
                s += __shfl_xor(s, off, 64);
            const float pw = __expf(s);
            l += pw;
            o0.x = fmaf(pw, a0.x, o0.x); o0.y = fmaf(pw, a0.y, o0.y);
            o0.z = fmaf(pw, a0.z, o0.z); o0.w = fmaf(pw, a0.w, o0.w);
            o1.x = fmaf(pw, a1.x, o1.x); o1.y = fmaf(pw, a1.y, o1.y);
            o1.z = fmaf(pw, a1.z, o1.z); o1.w = fmaf(pw, a1.w, o1.w);
            o2.x = fmaf(pw, a2.x, o2.x); o2.y = fmaf(pw, a2.y, o2.y);
            o2.w = fmaf(pw, a2.w, o2.w); o2.z = fmaf(pw, a2.z, o2.z);
        }
    }

    // Combine the block's 4 wave partials in LDS (plain sums), write one partial.
    __shared__ float sl[4];
    __shared__ float so[4][Ec];
    if (lane == 0) sl[wave] = l;
    *reinterpret_cast<float4*>(&so[wave][0 * 256 + 4 * lane]) = o0;
    *reinterpret_cast<float4*>(&so[wave][1 * 256 + 4 * lane]) = o1;
    *reinterpret_cast<float4*>(&so[wave][2 * 256 + 4 * lane]) = o2;
    __syncthreads();

    float* part = parts + ((long)b * C + c) * PSTRIDE;
    if (threadIdx.x == 0) part[0] = sl[0] + sl[1] + sl[2] + sl[3];
    if (threadIdx.x < 192) {
        const int e = 4 * threadIdx.x;
        float4 s0 = *reinterpret_cast<float4*>(&so[0][e]);
        float4 s1 = *reinterpret_cast<float4*>(&so[1][e]);
        float4 s2 = *reinterpret_cast<float4*>(&so[2][e]);
        float4 s3 = *reinterpret_cast<float4*>(&so[3][e]);
        float4 rs = make_float4(s0.x + s1.x + s2.x + s3.x,
                                s0.y + s1.y + s2.y + s3.y,
                                s0.z + s1.z + s2.z + s3.z,
                                s0.w + s1.w + s2.w + s3.w);
        *reinterpret_cast<float4*>(part + 4 + e) = rs;
    }
}

// Kernel 2: plain-sum combine of C partials per batch row + one divide.
// grid = (B, 3); each block handles 256 output features. Fully unrolled.
template<int C>
__global__ __launch_bounds__(256) void attn_reduce(
    const float* __restrict__ parts, float* __restrict__ out)
{
    const int b   = blockIdx.x;
    const int tid = threadIdx.x;
    const float* pb = parts + (long)b * C * PSTRIDE;

    float lsum = 0.0f;
#pragma unroll
    for (int k = 0; k < C; ++k) lsum += pb[k * PSTRIDE];

    const int e = blockIdx.y * 256 + tid;
    float acc = 0.0f;
#pragma unroll
    for (int k = 0; k < C; ++k) acc += pb[k * PSTRIDE + 4 + e];

    out[b * Ec + e] = acc / lsum;
}

template<int C>
static void run_pipeline(const float* ctx, const int* mask, const float* vw,
                         float* ws, float* out, hipStream_t stream)
{
    attn_partial<C><<<dim3(Bc * C), 256, 0, stream>>>(ctx, mask, vw, ws);
    attn_reduce<C><<<dim3(Bc, 3), 256, 0, stream>>>(ws, out);
}

extern "C" void kernel_launch(void* const* d_in, const int* in_sizes, int n_in,
                              void* d_out, int out_size, void* d_ws, size_t ws_size,
                              hipStream_t stream)
{
    (void)in_sizes; (void)n_in; (void)out_size;
    // setup_inputs order: query[0] (unused — softmax shift-invariant),
    // context[1], mask[2], v_w[3].
    const float* ctx  = (const float*)d_in[1];
    const int*   mask = (const int*)d_in[2];
    const float* vw   = (const float*)d_in[3];
    float* out = (float*)d_out;
    float* ws  = (float*)d_ws;

    const size_t need32 = (size_t)Bc * 32 * PSTRIDE * sizeof(float);
    const size_t need8  = (size_t)Bc * 8  * PSTRIDE * sizeof(float);
    const size_t need2  = (size_t)Bc * 2  * PSTRIDE * sizeof(float);

    if (ws_size >= need32)     run_pipeline<32>(ctx, mask, vw, ws, out, stream);
    else if (ws_size >= need8) run_pipeline<8>(ctx, mask, vw, ws, out, stream);
    else if (ws_size >= need2) run_pipeline<2>(ctx, mask, vw, ws, out, stream);
    else                       run_pipeline<1>(ctx, mask, vw, ws, out, stream);
}